// Round 5
// baseline (280.715 us; speedup 1.0000x reference)
//
#include <hip/hip_runtime.h>
#include <hip/hip_cooperative_groups.h>
#include <math.h>

namespace cg = cooperative_groups;

#define NN 8192
#define MM 4096
#define DD 128
#define TDIM 32
#define H1DIM 64
#define H2DIM 32
#define FEAT (3*DD + TDIM)   // 416
#define KGROUPS (FEAT/4)     // 104
#define MAXK 256
#define BIGF 1e30f
#define PREP_N (FEAT*H1DIM + H1DIM*H2DIM + MM)   // 32768

typedef float fvec4 __attribute__((ext_vector_type(4)));

// One cooperative kernel, 4 phases separated by grid.sync():
//   P0 prep:  pack W1 -> W1P (lane-coalesced float4 groups), W2 -> W2T, zero cnt
//   P1 csc:   dense H -> per-hyperedge node index lists (atomic append)
//   P2 stats: per-edge mean/sigma/range over member node embeddings -> feat
//   P3 mlp:   416 -> 64 -> 32 -> 1 sigmoid (blocks 0..255 only, block-uniform)
__global__ __launch_bounds__(256, 4) void mega_kernel(
        const float* __restrict__ x,   const float* __restrict__ H,
        const float* __restrict__ tptr,const float* __restrict__ Wt,
        const float* __restrict__ bt,
        const float* __restrict__ W1,  const float* __restrict__ b1,
        const float* __restrict__ W2,  const float* __restrict__ b2,
        const float* __restrict__ W3,  const float* __restrict__ b3,
        float* __restrict__ out,
        int* __restrict__ cnt, int* __restrict__ idxlist,
        float* __restrict__ feat, float* __restrict__ W1P, float* __restrict__ W2T) {
    cg::grid_group grid = cg::this_grid();
    const int tid  = threadIdx.x;
    const int gtid = blockIdx.x * 256 + tid;
    const int nthr = gridDim.x * 256;

    // ---------------- P0: prep ----------------
    for (int i = gtid; i < PREP_N; i += nthr) {
        if (i < FEAT * H1DIM) {
            int c = i & 3, j = (i >> 2) & 63, g = i >> 8;
            W1P[i] = W1[j * FEAT + g * 4 + c];         // W1P4[g*64+j] = W1[j][4g..]
        } else if (i < FEAT * H1DIM + H1DIM * H2DIM) {
            int t2 = i - FEAT * H1DIM;
            W2T[t2] = W2[(t2 & 31) * H1DIM + (t2 >> 5)];
        } else {
            cnt[i - FEAT * H1DIM - H1DIM * H2DIM] = 0;
        }
    }
    grid.sync();

    // ---------------- P1: build CSC ----------------
    {
        const fvec4* H4 = reinterpret_cast<const fvec4*>(H);
        const int total4 = NN * MM / 4;                 // 8,388,608
        for (int i4 = gtid; i4 < total4; i4 += nthr) {  // coalesced, deep MLP
            fvec4 v = __builtin_nontemporal_load(&H4[i4]);
            if (v.x != 0.f || v.y != 0.f || v.z != 0.f || v.w != 0.f) {
                int base = i4 * 4;
                int n    = base >> 12;                  // node (row), MM=4096
                int mcol = base & (MM - 1);             // hyperedge (col)
                float vals[4] = {v.x, v.y, v.z, v.w};
                #pragma unroll
                for (int c = 0; c < 4; ++c) {
                    if (vals[c] != 0.0f) {
                        int p = atomicAdd(&cnt[mcol + c], 1);
                        if (p < MAXK) idxlist[(mcol + c) * MAXK + p] = n;
                    }
                }
            }
        }
    }
    grid.sync();

    // ---------------- P2: stats (one edge per wave; lane owns d=2l,2l+1) ----
    const int wave = tid >> 6, lane = tid & 63;
    {
        const int gwave  = blockIdx.x * 4 + wave;
        const int nwaves = gridDim.x * 4;
        const float tval = tptr[0];
        for (int m = gwave; m < MM; m += nwaves) {
            int K = cnt[m]; if (K > MAXK) K = MAXK;
            const int* lst = idxlist + m * MAXK;
            float sx = 0.f, sy = 0.f, s2x = 0.f, s2y = 0.f;
            float mxx = -BIGF, mxy = -BIGF, mnx = BIGF, mny = BIGF;
            const float* xb = x + 2 * lane;
            int i = 0;
            for (; i + 4 <= K; i += 4) {
                int4 nv = *reinterpret_cast<const int4*>(lst + i);   // uniform
                float2 v0 = *reinterpret_cast<const float2*>(xb + nv.x * DD);
                float2 v1 = *reinterpret_cast<const float2*>(xb + nv.y * DD);
                float2 v2 = *reinterpret_cast<const float2*>(xb + nv.z * DD);
                float2 v3 = *reinterpret_cast<const float2*>(xb + nv.w * DD);
                sx  += (v0.x + v1.x) + (v2.x + v3.x);
                sy  += (v0.y + v1.y) + (v2.y + v3.y);
                s2x += (v0.x*v0.x + v1.x*v1.x) + (v2.x*v2.x + v3.x*v3.x);
                s2y += (v0.y*v0.y + v1.y*v1.y) + (v2.y*v2.y + v3.y*v3.y);
                mxx = fmaxf(mxx, fmaxf(fmaxf(v0.x, v1.x), fmaxf(v2.x, v3.x)));
                mxy = fmaxf(mxy, fmaxf(fmaxf(v0.y, v1.y), fmaxf(v2.y, v3.y)));
                mnx = fminf(mnx, fminf(fminf(v0.x, v1.x), fminf(v2.x, v3.x)));
                mny = fminf(mny, fminf(fminf(v0.y, v1.y), fminf(v2.y, v3.y)));
            }
            for (; i < K; ++i) {
                float2 v = *reinterpret_cast<const float2*>(xb + lst[i] * DD);
                sx += v.x; sy += v.y; s2x += v.x*v.x; s2y += v.y*v.y;
                mxx = fmaxf(mxx, v.x); mxy = fmaxf(mxy, v.y);
                mnx = fminf(mnx, v.x); mny = fminf(mny, v.y);
            }
            float deg = (K > 0) ? (float)K : 1.0f;
            float mux = sx / deg, muy = sy / deg;
            float sgx = sqrtf(fmaxf(s2x / deg - mux * mux, 1e-8f));
            float sgy = sqrtf(fmaxf(s2y / deg - muy * muy, 1e-8f));
            float dlx = (K > 0) ? (mxx - mnx) : 0.0f;
            float dly = (K > 0) ? (mxy - mny) : 0.0f;
            float* f = feat + m * FEAT;
            *reinterpret_cast<float2*>(f + 2*lane)          = make_float2(mux, muy);
            *reinterpret_cast<float2*>(f + DD + 2*lane)     = make_float2(sgx, sgy);
            *reinterpret_cast<float2*>(f + 2*DD + 2*lane)   = make_float2(dlx, dly);
            if (lane < TDIM)
                f[3*DD + lane] = fmaxf(tval * Wt[lane] + bt[lane], 0.0f);
        }
    }
    grid.sync();

    // ---------------- P3: MLP (blocks 0..255; block-uniform guard) ----------
    if (blockIdx.x < MM / 16) {
        int rbase = blockIdx.x * 16 + wave * 4;
        const float4* W1P4 = reinterpret_cast<const float4*>(W1P);
        const float4* f0 = reinterpret_cast<const float4*>(feat + (rbase + 0) * FEAT);
        const float4* f1 = reinterpret_cast<const float4*>(feat + (rbase + 1) * FEAT);
        const float4* f2 = reinterpret_cast<const float4*>(feat + (rbase + 2) * FEAT);
        const float4* f3 = reinterpret_cast<const float4*>(feat + (rbase + 3) * FEAT);

        float bb = b1[lane];
        float acc0 = bb, acc1 = bb, acc2 = bb, acc3 = bb;
        #pragma unroll 4
        for (int g = 0; g < KGROUPS; ++g) {
            float4 w = W1P4[g * H1DIM + lane];        // coalesced 1KB/wave
            float4 a0 = f0[g];                         // uniform broadcasts
            float4 a1 = f1[g];
            float4 a2 = f2[g];
            float4 a3 = f3[g];
            acc0 += a0.x*w.x + a0.y*w.y + a0.z*w.z + a0.w*w.w;
            acc1 += a1.x*w.x + a1.y*w.y + a1.z*w.z + a1.w*w.w;
            acc2 += a2.x*w.x + a2.y*w.y + a2.z*w.z + a2.w*w.w;
            acc3 += a3.x*w.x + a3.y*w.y + a3.z*w.z + a3.w*w.w;
        }

        __shared__ float hs1[16][H1DIM];
        hs1[wave*4 + 0][lane] = fmaxf(acc0, 0.f);
        hs1[wave*4 + 1][lane] = fmaxf(acc1, 0.f);
        hs1[wave*4 + 2][lane] = fmaxf(acc2, 0.f);
        hs1[wave*4 + 3][lane] = fmaxf(acc3, 0.f);
        __syncthreads();

        int j2 = lane & 31;
        int kh = (lane >> 5) * 32;
        float w3v = W3[j2];
        float b2v = b2[j2];
        #pragma unroll
        for (int r = 0; r < 4; ++r) {
            int row = wave * 4 + r;
            float a2 = 0.f;
            #pragma unroll
            for (int kk = 0; kk < 32; ++kk) {
                int k = kh + kk;
                a2 += hs1[row][k] * W2T[k * H2DIM + j2];
            }
            a2 += __shfl_xor(a2, 32);
            float h2 = fmaxf(a2 + b2v, 0.f);
            float p = h2 * w3v;
            p += __shfl_xor(p, 16);
            p += __shfl_xor(p, 8);
            p += __shfl_xor(p, 4);
            p += __shfl_xor(p, 2);
            p += __shfl_xor(p, 1);
            if (lane == 0) out[rbase + r] = 1.f / (1.f + expf(-(p + b3[0])));
        }
    }
}

extern "C" void kernel_launch(void* const* d_in, const int* in_sizes, int n_in,
                              void* d_out, int out_size, void* d_ws, size_t ws_size,
                              hipStream_t stream) {
    const float* x   = (const float*)d_in[0];   // (N, D)
    const float* H   = (const float*)d_in[1];   // (N, M)
    const float* t   = (const float*)d_in[2];   // (1,)
    const float* Wt  = (const float*)d_in[3];   // (TDIM, 1)
    const float* bt  = (const float*)d_in[4];   // (TDIM,)
    const float* W1  = (const float*)d_in[5];   // (64, 416)
    const float* b1  = (const float*)d_in[6];
    const float* W2  = (const float*)d_in[7];   // (32, 64)
    const float* b2  = (const float*)d_in[8];
    const float* W3  = (const float*)d_in[9];   // (1, 32)
    const float* b3  = (const float*)d_in[10];
    float* out = (float*)d_out;

    // workspace layout
    int* cnt     = (int*)d_ws;                            // M ints (16 KB)
    int* idxlist = cnt + MM;                              // M*MAXK ints (4 MB)
    float* feat  = (float*)(idxlist + (size_t)MM * MAXK); // M*FEAT floats (6.8 MB)
    float* W1P   = feat + (size_t)MM * FEAT;              // 26624 floats
    float* W2T   = W1P + FEAT * H1DIM;                    // 2048 floats

    // co-resident grid sizing (host-only queries; capture-safe)
    int occ = 1;
    hipOccupancyMaxActiveBlocksPerMultiprocessor(&occ, mega_kernel, 256, 0);
    if (occ < 1) occ = 1;
    int ncu = 256;
    hipDeviceGetAttribute(&ncu, hipDeviceAttributeMultiprocessorCount, 0);
    int nblocks = occ * ncu;
    if (nblocks > 1024) nblocks = 1024;
    if (nblocks < MM / 16) nblocks = MM / 16;             // P3 needs >= 256 blocks

    void* args[] = {
        (void*)&x, (void*)&H, (void*)&t, (void*)&Wt, (void*)&bt,
        (void*)&W1, (void*)&b1, (void*)&W2, (void*)&b2, (void*)&W3, (void*)&b3,
        (void*)&out, (void*)&cnt, (void*)&idxlist, (void*)&feat,
        (void*)&W1P, (void*)&W2T
    };
    hipLaunchCooperativeKernel((const void*)mega_kernel, dim3(nblocks), dim3(256),
                               args, 0, stream);
}

// Round 6
// 62.885 us; speedup vs baseline: 4.4639x; 4.4639x over previous
//
#include <hip/hip_runtime.h>
#include <math.h>

#define NN 8192
#define MM 4096
#define DD 128
#define TDIM 32
#define H1DIM 64
#define H2DIM 32
#define FEAT (3*DD + TDIM)   // 416
#define KGROUPS (FEAT/4)     // 104
#define MAXK 256
#define BIGF 1e30f
#define PACK_N (FEAT*H1DIM + H1DIM*H2DIM)   // 28672

typedef float fvec4 __attribute__((ext_vector_type(4)));

// Node 2: dense H (N x M, row-major) -> per-hyperedge node index lists.
// 4 float4s per thread, fully unrolled (deep MLP). NO nontemporal hint:
// H (134 MB) fits in the 256 MB Infinity Cache, so steady-state graph
// replays are L3-served. Block 0 additionally packs W1 -> W1P (lane-
// coalesced float4 groups) and W2 -> W2T, hidden under the scan.
__global__ void csc_pack(const float* __restrict__ H,
                         const float* __restrict__ W1, const float* __restrict__ W2,
                         int* __restrict__ cnt, int* __restrict__ idxlist,
                         float* __restrict__ W1P, float* __restrict__ W2T) {
    const int tid = threadIdx.x;
    if (blockIdx.x == 0) {
        for (int i = tid; i < PACK_N; i += 256) {
            if (i < FEAT * H1DIM) {
                int c = i & 3, j = (i >> 2) & 63, g = i >> 8;
                W1P[i] = W1[j * FEAT + g * 4 + c];      // W1P4[g*64+j] = W1[j][4g..]
            } else {
                int t2 = i - FEAT * H1DIM;
                W2T[t2] = W2[(t2 & 31) * H1DIM + (t2 >> 5)];
            }
        }
    }
    const fvec4* H4 = reinterpret_cast<const fvec4*>(H);
    int t0 = blockIdx.x * 1024 + tid;
    #pragma unroll
    for (int k = 0; k < 4; ++k) {
        int idx4 = t0 + k * 256;
        fvec4 v = H4[idx4];
        if (v.x != 0.f || v.y != 0.f || v.z != 0.f || v.w != 0.f) {
            int base = idx4 * 4;
            int n    = base >> 12;              // node (row), MM=4096
            int mcol = base & (MM - 1);         // hyperedge (col)
            float vals[4] = {v.x, v.y, v.z, v.w};
            #pragma unroll
            for (int c = 0; c < 4; ++c) {
                if (vals[c] != 0.0f) {
                    int p = atomicAdd(&cnt[mcol + c], 1);
                    if (p < MAXK) idxlist[(mcol + c) * MAXK + p] = n;
                }
            }
        }
    }
}

// Node 3: fused stats + MLP. 1024 blocks x 256 threads; block owns 4 edges.
// Phase A: wave w computes edge (blockIdx*4+w)'s mu/sigma/range into LDS
//          (lane owns dims 2l, 2l+1 via float2 gathers of x rows).
// Phase B: wave 0 runs the 416->64->32->1 MLP for all 4 rows from LDS
//          (4 rows/wave amortizes the coalesced W1P stream).
__global__ __launch_bounds__(256) void stats_mlp(
        const float* __restrict__ x,
        const int* __restrict__ cnt, const int* __restrict__ idxlist,
        const float* __restrict__ tptr, const float* __restrict__ Wt,
        const float* __restrict__ bt,
        const float* __restrict__ W1P, const float* __restrict__ b1,
        const float* __restrict__ W2T, const float* __restrict__ b2,
        const float* __restrict__ W3, const float* __restrict__ b3,
        float* __restrict__ out) {
    const int tid = threadIdx.x;
    const int wave = tid >> 6, lane = tid & 63;
    const int m = blockIdx.x * 4 + wave;

    __shared__ float lsf[4][FEAT];     // feature rows for the block's 4 edges
    __shared__ float hs1[4][H1DIM];    // layer-1 activations (wave 0 only)

    // ---- Phase A: stats ----
    {
        int K = cnt[m]; if (K > MAXK) K = MAXK;
        const int* lst = idxlist + m * MAXK;
        float sx = 0.f, sy = 0.f, s2x = 0.f, s2y = 0.f;
        float mxx = -BIGF, mxy = -BIGF, mnx = BIGF, mny = BIGF;
        const float* xb = x + 2 * lane;
        int i = 0;
        for (; i + 4 <= K; i += 4) {
            int4 nv = *reinterpret_cast<const int4*>(lst + i);   // wave-uniform
            float2 v0 = *reinterpret_cast<const float2*>(xb + nv.x * DD);
            float2 v1 = *reinterpret_cast<const float2*>(xb + nv.y * DD);
            float2 v2 = *reinterpret_cast<const float2*>(xb + nv.z * DD);
            float2 v3 = *reinterpret_cast<const float2*>(xb + nv.w * DD);
            sx  += (v0.x + v1.x) + (v2.x + v3.x);
            sy  += (v0.y + v1.y) + (v2.y + v3.y);
            s2x += (v0.x*v0.x + v1.x*v1.x) + (v2.x*v2.x + v3.x*v3.x);
            s2y += (v0.y*v0.y + v1.y*v1.y) + (v2.y*v2.y + v3.y*v3.y);
            mxx = fmaxf(mxx, fmaxf(fmaxf(v0.x, v1.x), fmaxf(v2.x, v3.x)));
            mxy = fmaxf(mxy, fmaxf(fmaxf(v0.y, v1.y), fmaxf(v2.y, v3.y)));
            mnx = fminf(mnx, fminf(fminf(v0.x, v1.x), fminf(v2.x, v3.x)));
            mny = fminf(mny, fminf(fminf(v0.y, v1.y), fminf(v2.y, v3.y)));
        }
        for (; i < K; ++i) {
            float2 v = *reinterpret_cast<const float2*>(xb + lst[i] * DD);
            sx += v.x; sy += v.y; s2x += v.x*v.x; s2y += v.y*v.y;
            mxx = fmaxf(mxx, v.x); mxy = fmaxf(mxy, v.y);
            mnx = fminf(mnx, v.x); mny = fminf(mny, v.y);
        }
        float deg = (K > 0) ? (float)K : 1.0f;
        float mux = sx / deg, muy = sy / deg;
        float sgx = sqrtf(fmaxf(s2x / deg - mux * mux, 1e-8f));
        float sgy = sqrtf(fmaxf(s2y / deg - muy * muy, 1e-8f));
        float dlx = (K > 0) ? (mxx - mnx) : 0.0f;
        float dly = (K > 0) ? (mxy - mny) : 0.0f;
        float* f = lsf[wave];
        f[2*lane]            = mux;  f[2*lane + 1]          = muy;
        f[DD + 2*lane]       = sgx;  f[DD + 2*lane + 1]     = sgy;
        f[2*DD + 2*lane]     = dlx;  f[2*DD + 2*lane + 1]   = dly;
        if (lane < TDIM)
            f[3*DD + lane] = fmaxf(tptr[0] * Wt[lane] + bt[lane], 0.0f);
    }
    __syncthreads();

    // ---- Phase B: MLP on wave 0 (4 rows) ----
    if (wave == 0) {
        const float4* W1P4 = reinterpret_cast<const float4*>(W1P);
        const float4* f0 = reinterpret_cast<const float4*>(lsf[0]);
        const float4* f1 = reinterpret_cast<const float4*>(lsf[1]);
        const float4* f2 = reinterpret_cast<const float4*>(lsf[2]);
        const float4* f3 = reinterpret_cast<const float4*>(lsf[3]);

        float bb = b1[lane];
        float acc0 = bb, acc1 = bb, acc2 = bb, acc3 = bb;
        #pragma unroll 4
        for (int g = 0; g < KGROUPS; ++g) {
            float4 w = W1P4[g * H1DIM + lane];    // coalesced 1KB/wave, L2-res
            float4 a0 = f0[g];                     // LDS broadcasts
            float4 a1 = f1[g];
            float4 a2 = f2[g];
            float4 a3 = f3[g];
            acc0 += a0.x*w.x + a0.y*w.y + a0.z*w.z + a0.w*w.w;
            acc1 += a1.x*w.x + a1.y*w.y + a1.z*w.z + a1.w*w.w;
            acc2 += a2.x*w.x + a2.y*w.y + a2.z*w.z + a2.w*w.w;
            acc3 += a3.x*w.x + a3.y*w.y + a3.z*w.z + a3.w*w.w;
        }
        hs1[0][lane] = fmaxf(acc0, 0.f);
        hs1[1][lane] = fmaxf(acc1, 0.f);
        hs1[2][lane] = fmaxf(acc2, 0.f);
        hs1[3][lane] = fmaxf(acc3, 0.f);

        int j2 = lane & 31;
        int kh = (lane >> 5) * 32;
        float w3v = W3[j2];
        float b2v = b2[j2];
        #pragma unroll
        for (int r = 0; r < 4; ++r) {
            float a2 = 0.f;
            #pragma unroll
            for (int kk = 0; kk < 32; ++kk) {
                int k = kh + kk;
                a2 += hs1[r][k] * W2T[k * H2DIM + j2];  // LDS bcast x coalesced
            }
            a2 += __shfl_xor(a2, 32);
            float h2 = fmaxf(a2 + b2v, 0.f);
            float p = h2 * w3v;
            p += __shfl_xor(p, 16);
            p += __shfl_xor(p, 8);
            p += __shfl_xor(p, 4);
            p += __shfl_xor(p, 2);
            p += __shfl_xor(p, 1);
            if (lane == 0) out[blockIdx.x * 4 + r] = 1.f / (1.f + expf(-(p + b3[0])));
        }
    }
}

extern "C" void kernel_launch(void* const* d_in, const int* in_sizes, int n_in,
                              void* d_out, int out_size, void* d_ws, size_t ws_size,
                              hipStream_t stream) {
    const float* x   = (const float*)d_in[0];   // (N, D)
    const float* H   = (const float*)d_in[1];   // (N, M)
    const float* t   = (const float*)d_in[2];   // (1,)
    const float* Wt  = (const float*)d_in[3];   // (TDIM, 1)
    const float* bt  = (const float*)d_in[4];   // (TDIM,)
    const float* W1  = (const float*)d_in[5];   // (64, 416)
    const float* b1  = (const float*)d_in[6];
    const float* W2  = (const float*)d_in[7];   // (32, 64)
    const float* b2  = (const float*)d_in[8];
    const float* W3  = (const float*)d_in[9];   // (1, 32)
    const float* b3  = (const float*)d_in[10];
    float* out = (float*)d_out;

    // workspace layout
    int* cnt     = (int*)d_ws;                            // M ints (16 KB)
    int* idxlist = cnt + MM;                              // M*MAXK ints (4 MB)
    float* W1P   = (float*)(idxlist + (size_t)MM * MAXK); // 26624 floats
    float* W2T   = W1P + FEAT * H1DIM;                    // 2048 floats

    hipMemsetAsync(cnt, 0, MM * sizeof(int), stream);
    csc_pack<<<NN * MM / 4 / 1024, 256, 0, stream>>>(H, W1, W2, cnt, idxlist, W1P, W2T);
    stats_mlp<<<MM / 4, 256, 0, stream>>>(x, cnt, idxlist, t, Wt, bt,
                                          W1P, b1, W2T, b2, W3, b3, out);
}